// Round 5
// baseline (218.215 us; speedup 1.0000x reference)
//
#include <hip/hip_runtime.h>
#include <hip/hip_bf16.h>

// StochasticEnsemble: hard-routed 8-expert MLP.
// Round 5: transpose kernels eliminated — f32->bf16 transpose of W1/W2 is
// fused into the GEMM B-staging (register repack into XOR-chunk LDS layout,
// col-balanced => conflict-free). 5 launches total: memset, route(+convert),
// scan, gemm1, gemm2. Fast GEMM core unchanged (m97 shape: 128x128, BK=64).

#define BATCH 2048
#define ZD 128
#define HID 1024
#define OUTD 3072
#define NEXP 8

#define TMG 128
#define TNG 128
#define BKG 64
#define MAXTF 24          // max 128-row M-tiles

typedef short bf16x8 __attribute__((ext_vector_type(8)));   // 8 bf16 = 4 VGPRs
typedef float f32x4 __attribute__((ext_vector_type(4)));

// ---- workspace byte layout (ws_size = 384 MiB) ----
// 0        counts[8]
// 64       ntl[1]
// 128      texp[24]
// 256      perm[3072]               -> ends 12544
// 12544    bucket[8*2048]           -> ends 78080
// 78080    zb bf16 [2048*128]       -> ends 602368
// 602368   Hb bf16 [3072*1024]      -> ends 6893824

// Route + convert: 8 threads per sample; exact integral-fp32 hash; two-level
// atomics (LDS histogram -> one global atomicAdd per expert per block).
__global__ __launch_bounds__(256) void route_kernel(const float* __restrict__ z,
                                                    __hip_bfloat16* __restrict__ zb,
                                                    int* counts, int* bucket) {
    __shared__ int lcnt[NEXP];
    __shared__ int gbase[NEXP];
    int t = threadIdx.x;
    if (t < NEXP) lcnt[t] = 0;
    __syncthreads();

    int s = blockIdx.x * 32 + (t >> 3);          // sample
    int li = t & 7;                               // lane-in-sample
    const float* zp = z + (size_t)s * ZD + li * 16;
    float sum = 0.f;
    union { bf16x8 v8; __hip_bfloat16 h[8]; } u0, u1;
#pragma unroll
    for (int i = 0; i < 4; i++) {
        float4 v = ((const float4*)zp)[i];
        sum += floorf(fabsf(v.x) * 1000.0f) + floorf(fabsf(v.y) * 1000.0f) +
               floorf(fabsf(v.z) * 1000.0f) + floorf(fabsf(v.w) * 1000.0f);
        __hip_bfloat16* dst = (i < 2) ? &u0.h[i * 4] : &u1.h[(i - 2) * 4];
        dst[0] = __float2bfloat16(v.x);
        dst[1] = __float2bfloat16(v.y);
        dst[2] = __float2bfloat16(v.z);
        dst[3] = __float2bfloat16(v.w);
    }
    bf16x8* zo = (bf16x8*)(zb + (size_t)s * ZD + li * 16);
    zo[0] = u0.v8;
    zo[1] = u1.v8;

    sum += __shfl_down(sum, 4);
    sum += __shfl_down(sum, 2);
    sum += __shfl_down(sum, 1);
    int e = 0, lpos = 0;
    if (li == 0) {
        e = ((int)sum) & 7;
        lpos = atomicAdd(&lcnt[e], 1);
    }
    __syncthreads();
    if (t < NEXP) gbase[t] = atomicAdd(&counts[t], lcnt[t]);
    __syncthreads();
    if (li == 0) bucket[e * BATCH + gbase[e] + lpos] = s;
}

__global__ void scan_kernel(const int* __restrict__ counts, int* ntl,
                            int* texp, int* perm, const int* __restrict__ bucket) {
    __shared__ int soff[NEXP + 1];
    __shared__ int scnt[NEXP];
    if (threadIdx.x == 0) {
        int o = 0;
        for (int e = 0; e < NEXP; e++) {
            scnt[e] = counts[e];
            soff[e] = o;
            o += (scnt[e] + TMG - 1) & ~(TMG - 1);
        }
        soff[NEXP] = o;
        *ntl = o / TMG;
    }
    __syncthreads();
    int total = soff[NEXP];
    for (int r = threadIdx.x; r < total; r += blockDim.x) {
        int e = 0;
        while (r >= soff[e + 1]) e++;
        int i = r - soff[e];
        perm[r] = (i < scnt[e]) ? bucket[e * BATCH + i] : -1;
        if ((r & (TMG - 1)) == 0) texp[r / TMG] = e;
    }
}

// ---------------- fused GEMMs (m97 shape, B transposed in staging) ----------
// LDS tile layout: 16B chunk c of row r stored at elem (r*8 + (c ^ (r&7)))*8.
// A-staging: sr=tid>>3, sc=tid&7 (b128 copy from k-contig bf16).
// B-staging: bkc=tid&7 (k-chunk), bn=(tid>>3)*4 (n-group): 8 float4 n-coalesced
// loads of W f32 -> 4 bf16x8 k-chunks -> 4 ds_write_b128 (col-balanced).

__global__ __launch_bounds__(256, 3) void gemm1_fast(
    const __hip_bfloat16* __restrict__ zb, const float* __restrict__ W1,
    const float* __restrict__ b1, const int* __restrict__ ntl,
    const int* __restrict__ texp, const int* __restrict__ perm,
    __hip_bfloat16* __restrict__ H) {
    int mt = blockIdx.y;
    if (mt >= *ntl) return;
    int e = texp[mt];
    int n0 = blockIdx.x * TNG;

    __shared__ __align__(16) __hip_bfloat16 As[TMG * BKG];
    __shared__ __align__(16) __hip_bfloat16 Bs[TNG * BKG];
    __shared__ int rows_s[TMG];

    int tid = threadIdx.x;
    if (tid < TMG) rows_s[tid] = perm[mt * TMG + tid];
    __syncthreads();

    int lane = tid & 63, wave = tid >> 6;
    int cc = lane & 15, q = lane >> 4;
    int mw = (wave >> 1) * 64, nw = (wave & 1) * 64;

    // A staging
    int sr = tid >> 3, sc = tid & 7;
    int awbase = sr * 64 + (sc ^ (sr & 7)) * 8;     // + p*2048
    const __hip_bfloat16* Arp[4];
#pragma unroll
    for (int p = 0; p < 4; p++) {
        int r = rows_s[p * 32 + sr];
        if (r < 0) r = 0;
        Arp[p] = zb + (size_t)r * ZD + sc * 8;
    }
    // B staging (fused transpose from W1 f32)
    int bkc = tid & 7, bn = (tid >> 3) * 4;
    const float* Bgf = W1 + (size_t)e * ZD * HID + (size_t)(bkc * 8) * HID + n0 + bn;
    int bwb[4];
#pragma unroll
    for (int j = 0; j < 4; j++)
        bwb[j] = (bn + j) * 64 + ((bkc ^ ((bn + j) & 7))) * 8;

    int A0 = (mw + cc) * 64, B0 = (nw + cc) * 64;
    int X0 = (q ^ (cc & 7)) * 8, X1 = ((4 + q) ^ (cc & 7)) * 8;

    float bias[4];
#pragma unroll
    for (int j = 0; j < 4; j++) bias[j] = b1[(size_t)e * HID + n0 + nw + j * 16 + cc];

    f32x4 zero4 = {0.f, 0.f, 0.f, 0.f};
    f32x4 acc[4][4];
#pragma unroll
    for (int i = 0; i < 4; i++)
#pragma unroll
        for (int j = 0; j < 4; j++) acc[i][j] = zero4;

    bf16x8 ga[4];
    union { bf16x8 v8; __hip_bfloat16 h[8]; } gb[4];
#pragma unroll
    for (int p = 0; p < 4; p++) ga[p] = *(const bf16x8*)(Arp[p]);
#pragma unroll
    for (int i = 0; i < 8; i++) {
        float4 v = *(const float4*)(Bgf + (size_t)i * HID);
        gb[0].h[i] = __float2bfloat16(v.x);
        gb[1].h[i] = __float2bfloat16(v.y);
        gb[2].h[i] = __float2bfloat16(v.z);
        gb[3].h[i] = __float2bfloat16(v.w);
    }
#pragma unroll
    for (int it = 0; it < ZD / BKG; ++it) {
        __syncthreads();
#pragma unroll
        for (int p = 0; p < 4; p++) *(bf16x8*)(As + awbase + p * 2048) = ga[p];
#pragma unroll
        for (int j = 0; j < 4; j++) *(bf16x8*)(Bs + bwb[j]) = gb[j].v8;
        __syncthreads();
        if (it + 1 < ZD / BKG) {
#pragma unroll
            for (int p = 0; p < 4; p++)
                ga[p] = *(const bf16x8*)(Arp[p] + (it + 1) * BKG);
#pragma unroll
            for (int i = 0; i < 8; i++) {
                float4 v = *(const float4*)(Bgf + (size_t)((it + 1) * BKG + i) * HID);
                gb[0].h[i] = __float2bfloat16(v.x);
                gb[1].h[i] = __float2bfloat16(v.y);
                gb[2].h[i] = __float2bfloat16(v.z);
                gb[3].h[i] = __float2bfloat16(v.w);
            }
        }
#pragma unroll
        for (int kh = 0; kh < 2; ++kh) {
            int X = kh ? X1 : X0;
            bf16x8 af[4], bfr[4];
#pragma unroll
            for (int i = 0; i < 4; i++) af[i] = *(const bf16x8*)(As + A0 + i * 1024 + X);
#pragma unroll
            for (int j = 0; j < 4; j++) bfr[j] = *(const bf16x8*)(Bs + B0 + j * 1024 + X);
#pragma unroll
            for (int i = 0; i < 4; i++)
#pragma unroll
                for (int j = 0; j < 4; j++)
                    acc[i][j] = __builtin_amdgcn_mfma_f32_16x16x32_bf16(af[i], bfr[j],
                                                                        acc[i][j], 0, 0, 0);
        }
    }
#pragma unroll
    for (int i = 0; i < 4; i++)
#pragma unroll
        for (int r = 0; r < 4; r++) {
            int m = mw + i * 16 + q * 4 + r;
            __hip_bfloat16* hp = H + (size_t)(mt * TMG + m) * HID + n0 + nw + cc;
#pragma unroll
            for (int j = 0; j < 4; j++)
                hp[j * 16] = __float2bfloat16(fmaxf(acc[i][j][r] + bias[j], 0.f));
        }
}

__global__ __launch_bounds__(256, 3) void gemm2_fast(
    const __hip_bfloat16* __restrict__ H, const float* __restrict__ W2,
    const float* __restrict__ b2, const int* __restrict__ ntl,
    const int* __restrict__ texp, const int* __restrict__ perm,
    float* __restrict__ out) {
    int mt = blockIdx.y;
    if (mt >= *ntl) return;
    int e = texp[mt];
    int n0 = blockIdx.x * TNG;

    __shared__ __align__(16) __hip_bfloat16 As[TMG * BKG];
    __shared__ __align__(16) __hip_bfloat16 Bs[TNG * BKG];
    __shared__ int rows_s[TMG];

    int tid = threadIdx.x;
    if (tid < TMG) rows_s[tid] = perm[mt * TMG + tid];

    int lane = tid & 63, wave = tid >> 6;
    int cc = lane & 15, q = lane >> 4;
    int mw = (wave >> 1) * 64, nw = (wave & 1) * 64;

    // A staging (H bf16, k-contig)
    int sr = tid >> 3, sc = tid & 7;
    int awbase = sr * 64 + (sc ^ (sr & 7)) * 8;     // + p*2048
    const __hip_bfloat16* Ag = H + ((size_t)mt * TMG + sr) * HID + sc * 8;
    // B staging (fused transpose from W2 f32)
    int bkc = tid & 7, bn = (tid >> 3) * 4;
    const float* Bgf = W2 + (size_t)e * HID * OUTD + (size_t)(bkc * 8) * OUTD + n0 + bn;
    int bwb[4];
#pragma unroll
    for (int j = 0; j < 4; j++)
        bwb[j] = (bn + j) * 64 + ((bkc ^ ((bn + j) & 7))) * 8;

    int A0 = (mw + cc) * 64, B0 = (nw + cc) * 64;
    int X0 = (q ^ (cc & 7)) * 8, X1 = ((4 + q) ^ (cc & 7)) * 8;

    float bias[4];
#pragma unroll
    for (int j = 0; j < 4; j++) bias[j] = b2[(size_t)e * OUTD + n0 + nw + j * 16 + cc];

    f32x4 zero4 = {0.f, 0.f, 0.f, 0.f};
    f32x4 acc[4][4];
#pragma unroll
    for (int i = 0; i < 4; i++)
#pragma unroll
        for (int j = 0; j < 4; j++) acc[i][j] = zero4;

    bf16x8 ga[4];
    union { bf16x8 v8; __hip_bfloat16 h[8]; } gb[4];
#pragma unroll
    for (int p = 0; p < 4; p++) ga[p] = *(const bf16x8*)(Ag + (size_t)p * 32 * HID);
#pragma unroll
    for (int i = 0; i < 8; i++) {
        float4 v = *(const float4*)(Bgf + (size_t)i * OUTD);
        gb[0].h[i] = __float2bfloat16(v.x);
        gb[1].h[i] = __float2bfloat16(v.y);
        gb[2].h[i] = __float2bfloat16(v.z);
        gb[3].h[i] = __float2bfloat16(v.w);
    }
    for (int it = 0; it < HID / BKG; ++it) {
        __syncthreads();
#pragma unroll
        for (int p = 0; p < 4; p++) *(bf16x8*)(As + awbase + p * 2048) = ga[p];
#pragma unroll
        for (int j = 0; j < 4; j++) *(bf16x8*)(Bs + bwb[j]) = gb[j].v8;
        __syncthreads();
        if (it + 1 < HID / BKG) {
            int k1 = (it + 1) * BKG;
#pragma unroll
            for (int p = 0; p < 4; p++)
                ga[p] = *(const bf16x8*)(Ag + (size_t)p * 32 * HID + k1);
#pragma unroll
            for (int i = 0; i < 8; i++) {
                float4 v = *(const float4*)(Bgf + (size_t)(k1 + i) * OUTD);
                gb[0].h[i] = __float2bfloat16(v.x);
                gb[1].h[i] = __float2bfloat16(v.y);
                gb[2].h[i] = __float2bfloat16(v.z);
                gb[3].h[i] = __float2bfloat16(v.w);
            }
        }
#pragma unroll
        for (int kh = 0; kh < 2; ++kh) {
            int X = kh ? X1 : X0;
            bf16x8 af[4], bfr[4];
#pragma unroll
            for (int i = 0; i < 4; i++) af[i] = *(const bf16x8*)(As + A0 + i * 1024 + X);
#pragma unroll
            for (int j = 0; j < 4; j++) bfr[j] = *(const bf16x8*)(Bs + B0 + j * 1024 + X);
#pragma unroll
            for (int i = 0; i < 4; i++)
#pragma unroll
                for (int j = 0; j < 4; j++)
                    acc[i][j] = __builtin_amdgcn_mfma_f32_16x16x32_bf16(af[i], bfr[j],
                                                                        acc[i][j], 0, 0, 0);
        }
    }
#pragma unroll
    for (int i = 0; i < 4; i++)
#pragma unroll
        for (int r = 0; r < 4; r++) {
            int m = mw + i * 16 + q * 4 + r;
            int orow = rows_s[m];
            if (orow >= 0) {
                float* op = out + (size_t)orow * OUTD + n0 + nw + cc;
#pragma unroll
                for (int j = 0; j < 4; j++) op[j * 16] = acc[i][j][r] + bias[j];
            }
        }
}

extern "C" void kernel_launch(void* const* d_in, const int* in_sizes, int n_in,
                              void* d_out, int out_size, void* d_ws, size_t ws_size,
                              hipStream_t stream) {
    const float* z  = (const float*)d_in[0];
    const float* W1 = (const float*)d_in[1];
    const float* b1 = (const float*)d_in[2];
    const float* W2 = (const float*)d_in[3];
    const float* b2 = (const float*)d_in[4];
    float* out = (float*)d_out;

    char* ws = (char*)d_ws;
    int* counts = (int*)ws;
    int* ntl    = (int*)(ws + 64);
    int* texp   = (int*)(ws + 128);
    int* perm   = (int*)(ws + 256);
    int* bucket = (int*)(ws + 12544);
    __hip_bfloat16* zb  = (__hip_bfloat16*)(ws + 78080);
    __hip_bfloat16* Hb  = (__hip_bfloat16*)(ws + 602368);

    hipMemsetAsync(counts, 0, 64, stream);
    hipLaunchKernelGGL(route_kernel, dim3(BATCH / 32), dim3(256), 0, stream,
                       z, zb, counts, bucket);
    hipLaunchKernelGGL(scan_kernel, dim3(1), dim3(256), 0, stream,
                       counts, ntl, texp, perm, bucket);
    hipLaunchKernelGGL(gemm1_fast, dim3(HID / TNG, MAXTF), dim3(256), 0, stream,
                       zb, W1, b1, ntl, texp, perm, Hb);
    hipLaunchKernelGGL(gemm2_fast, dim3(OUTD / TNG, MAXTF), dim3(256), 0, stream,
                       Hb, W2, b2, ntl, texp, perm, out);
}

// Round 6
// 202.416 us; speedup vs baseline: 1.0781x; 1.0781x over previous
//
#include <hip/hip_runtime.h>
#include <hip/hip_bf16.h>

// StochasticEnsemble: hard-routed 8-expert MLP.
// Round 6: gemm2 gets a single-barrier LDS double-buffer K-loop. Raw f32 B
// prefetch stays in registers across the MFMA phase; f32->bf16 convert is
// deferred to the next iteration's write phase so no vmcnt wait precedes the
// barrier. One __syncthreads per K-iter (was 2). gemm1/route/scan unchanged.

#define BATCH 2048
#define ZD 128
#define HID 1024
#define OUTD 3072
#define NEXP 8

#define TMG 128
#define TNG 128
#define BKG 64
#define MAXTF 24          // max 128-row M-tiles

typedef short bf16x8 __attribute__((ext_vector_type(8)));   // 8 bf16 = 4 VGPRs
typedef float f32x4 __attribute__((ext_vector_type(4)));

// ---- workspace byte layout (ws_size = 384 MiB) ----
// 0        counts[8]
// 64       ntl[1]
// 128      texp[24]
// 256      perm[3072]               -> ends 12544
// 12544    bucket[8*2048]           -> ends 78080
// 78080    zb bf16 [2048*128]       -> ends 602368
// 602368   Hb bf16 [3072*1024]      -> ends 6893824

__global__ __launch_bounds__(256) void route_kernel(const float* __restrict__ z,
                                                    __hip_bfloat16* __restrict__ zb,
                                                    int* counts, int* bucket) {
    __shared__ int lcnt[NEXP];
    __shared__ int gbase[NEXP];
    int t = threadIdx.x;
    if (t < NEXP) lcnt[t] = 0;
    __syncthreads();

    int s = blockIdx.x * 32 + (t >> 3);          // sample
    int li = t & 7;                               // lane-in-sample
    const float* zp = z + (size_t)s * ZD + li * 16;
    float sum = 0.f;
    union { bf16x8 v8; __hip_bfloat16 h[8]; } u0, u1;
#pragma unroll
    for (int i = 0; i < 4; i++) {
        float4 v = ((const float4*)zp)[i];
        sum += floorf(fabsf(v.x) * 1000.0f) + floorf(fabsf(v.y) * 1000.0f) +
               floorf(fabsf(v.z) * 1000.0f) + floorf(fabsf(v.w) * 1000.0f);
        __hip_bfloat16* dst = (i < 2) ? &u0.h[i * 4] : &u1.h[(i - 2) * 4];
        dst[0] = __float2bfloat16(v.x);
        dst[1] = __float2bfloat16(v.y);
        dst[2] = __float2bfloat16(v.z);
        dst[3] = __float2bfloat16(v.w);
    }
    bf16x8* zo = (bf16x8*)(zb + (size_t)s * ZD + li * 16);
    zo[0] = u0.v8;
    zo[1] = u1.v8;

    sum += __shfl_down(sum, 4);
    sum += __shfl_down(sum, 2);
    sum += __shfl_down(sum, 1);
    int e = 0, lpos = 0;
    if (li == 0) {
        e = ((int)sum) & 7;
        lpos = atomicAdd(&lcnt[e], 1);
    }
    __syncthreads();
    if (t < NEXP) gbase[t] = atomicAdd(&counts[t], lcnt[t]);
    __syncthreads();
    if (li == 0) bucket[e * BATCH + gbase[e] + lpos] = s;
}

__global__ void scan_kernel(const int* __restrict__ counts, int* ntl,
                            int* texp, int* perm, const int* __restrict__ bucket) {
    __shared__ int soff[NEXP + 1];
    __shared__ int scnt[NEXP];
    if (threadIdx.x == 0) {
        int o = 0;
        for (int e = 0; e < NEXP; e++) {
            scnt[e] = counts[e];
            soff[e] = o;
            o += (scnt[e] + TMG - 1) & ~(TMG - 1);
        }
        soff[NEXP] = o;
        *ntl = o / TMG;
    }
    __syncthreads();
    int total = soff[NEXP];
    for (int r = threadIdx.x; r < total; r += blockDim.x) {
        int e = 0;
        while (r >= soff[e + 1]) e++;
        int i = r - soff[e];
        perm[r] = (i < scnt[e]) ? bucket[e * BATCH + i] : -1;
        if ((r & (TMG - 1)) == 0) texp[r / TMG] = e;
    }
}

// ---------------- gemm1 (round-5 structure, K=128 = 2 iters) ----------------
__global__ __launch_bounds__(256, 3) void gemm1_fast(
    const __hip_bfloat16* __restrict__ zb, const float* __restrict__ W1,
    const float* __restrict__ b1, const int* __restrict__ ntl,
    const int* __restrict__ texp, const int* __restrict__ perm,
    __hip_bfloat16* __restrict__ H) {
    int mt = blockIdx.y;
    if (mt >= *ntl) return;
    int e = texp[mt];
    int n0 = blockIdx.x * TNG;

    __shared__ __align__(16) __hip_bfloat16 As[TMG * BKG];
    __shared__ __align__(16) __hip_bfloat16 Bs[TNG * BKG];
    __shared__ int rows_s[TMG];

    int tid = threadIdx.x;
    if (tid < TMG) rows_s[tid] = perm[mt * TMG + tid];
    __syncthreads();

    int lane = tid & 63, wave = tid >> 6;
    int cc = lane & 15, q = lane >> 4;
    int mw = (wave >> 1) * 64, nw = (wave & 1) * 64;

    int sr = tid >> 3, sc = tid & 7;
    int awbase = sr * 64 + (sc ^ (sr & 7)) * 8;     // + p*2048
    const __hip_bfloat16* Arp[4];
#pragma unroll
    for (int p = 0; p < 4; p++) {
        int r = rows_s[p * 32 + sr];
        if (r < 0) r = 0;
        Arp[p] = zb + (size_t)r * ZD + sc * 8;
    }
    int bkc = tid & 7, bn = (tid >> 3) * 4;
    const float* Bgf = W1 + (size_t)e * ZD * HID + (size_t)(bkc * 8) * HID + n0 + bn;
    int bwb[4];
#pragma unroll
    for (int j = 0; j < 4; j++)
        bwb[j] = (bn + j) * 64 + ((bkc ^ ((bn + j) & 7))) * 8;

    int A0 = (mw + cc) * 64, B0 = (nw + cc) * 64;
    int X0 = (q ^ (cc & 7)) * 8, X1 = ((4 + q) ^ (cc & 7)) * 8;

    float bias[4];
#pragma unroll
    for (int j = 0; j < 4; j++) bias[j] = b1[(size_t)e * HID + n0 + nw + j * 16 + cc];

    f32x4 zero4 = {0.f, 0.f, 0.f, 0.f};
    f32x4 acc[4][4];
#pragma unroll
    for (int i = 0; i < 4; i++)
#pragma unroll
        for (int j = 0; j < 4; j++) acc[i][j] = zero4;

    bf16x8 ga[4];
    union { bf16x8 v8; __hip_bfloat16 h[8]; } gb[4];
#pragma unroll
    for (int p = 0; p < 4; p++) ga[p] = *(const bf16x8*)(Arp[p]);
#pragma unroll
    for (int i = 0; i < 8; i++) {
        float4 v = *(const float4*)(Bgf + (size_t)i * HID);
        gb[0].h[i] = __float2bfloat16(v.x);
        gb[1].h[i] = __float2bfloat16(v.y);
        gb[2].h[i] = __float2bfloat16(v.z);
        gb[3].h[i] = __float2bfloat16(v.w);
    }
#pragma unroll
    for (int it = 0; it < ZD / BKG; ++it) {
        __syncthreads();
#pragma unroll
        for (int p = 0; p < 4; p++) *(bf16x8*)(As + awbase + p * 2048) = ga[p];
#pragma unroll
        for (int j = 0; j < 4; j++) *(bf16x8*)(Bs + bwb[j]) = gb[j].v8;
        __syncthreads();
        if (it + 1 < ZD / BKG) {
#pragma unroll
            for (int p = 0; p < 4; p++)
                ga[p] = *(const bf16x8*)(Arp[p] + (it + 1) * BKG);
#pragma unroll
            for (int i = 0; i < 8; i++) {
                float4 v = *(const float4*)(Bgf + (size_t)((it + 1) * BKG + i) * HID);
                gb[0].h[i] = __float2bfloat16(v.x);
                gb[1].h[i] = __float2bfloat16(v.y);
                gb[2].h[i] = __float2bfloat16(v.z);
                gb[3].h[i] = __float2bfloat16(v.w);
            }
        }
#pragma unroll
        for (int kh = 0; kh < 2; ++kh) {
            int X = kh ? X1 : X0;
            bf16x8 af[4], bfr[4];
#pragma unroll
            for (int i = 0; i < 4; i++) af[i] = *(const bf16x8*)(As + A0 + i * 1024 + X);
#pragma unroll
            for (int j = 0; j < 4; j++) bfr[j] = *(const bf16x8*)(Bs + B0 + j * 1024 + X);
#pragma unroll
            for (int i = 0; i < 4; i++)
#pragma unroll
                for (int j = 0; j < 4; j++)
                    acc[i][j] = __builtin_amdgcn_mfma_f32_16x16x32_bf16(af[i], bfr[j],
                                                                        acc[i][j], 0, 0, 0);
        }
    }
#pragma unroll
    for (int i = 0; i < 4; i++)
#pragma unroll
        for (int r = 0; r < 4; r++) {
            int m = mw + i * 16 + q * 4 + r;
            __hip_bfloat16* hp = H + (size_t)(mt * TMG + m) * HID + n0 + nw + cc;
#pragma unroll
            for (int j = 0; j < 4; j++)
                hp[j * 16] = __float2bfloat16(fmaxf(acc[i][j][r] + bias[j], 0.f));
        }
}

// ---------------- gemm2: single-barrier LDS double-buffer ----------------
// Per iter: cvt+write buf[cur]; issue raw loads for it+1 (f32 stays raw in
// VGPRs across the MFMA phase -> no vmcnt wait before the barrier); ONE
// __syncthreads; MFMA from buf[cur]. Writes to buf[1-cur] at it+1 are
// separated from it-1's reads by it's barrier.
__global__ __launch_bounds__(256, 2) void gemm2_fast(
    const __hip_bfloat16* __restrict__ H, const float* __restrict__ W2,
    const float* __restrict__ b2, const int* __restrict__ ntl,
    const int* __restrict__ texp, const int* __restrict__ perm,
    float* __restrict__ out) {
    int mt = blockIdx.y;
    if (mt >= *ntl) return;
    int e = texp[mt];
    int n0 = blockIdx.x * TNG;

    __shared__ __align__(16) __hip_bfloat16 As[2][TMG * BKG];   // 2 x 16 KB
    __shared__ __align__(16) __hip_bfloat16 Bs[2][TNG * BKG];   // 2 x 16 KB
    __shared__ int rows_s[TMG];

    int tid = threadIdx.x;
    if (tid < TMG) rows_s[tid] = perm[mt * TMG + tid];

    int lane = tid & 63, wave = tid >> 6;
    int cc = lane & 15, q = lane >> 4;
    int mw = (wave >> 1) * 64, nw = (wave & 1) * 64;

    int sr = tid >> 3, sc = tid & 7;
    int awbase = sr * 64 + (sc ^ (sr & 7)) * 8;     // + p*2048
    const __hip_bfloat16* Ag = H + ((size_t)mt * TMG + sr) * HID + sc * 8;
    int bkc = tid & 7, bn = (tid >> 3) * 4;
    const float* Bgf = W2 + (size_t)e * HID * OUTD + (size_t)(bkc * 8) * OUTD + n0 + bn;
    int bwb[4];
#pragma unroll
    for (int j = 0; j < 4; j++)
        bwb[j] = (bn + j) * 64 + ((bkc ^ ((bn + j) & 7))) * 8;

    int A0 = (mw + cc) * 64, B0 = (nw + cc) * 64;
    int X0 = (q ^ (cc & 7)) * 8, X1 = ((4 + q) ^ (cc & 7)) * 8;

    float bias[4];
#pragma unroll
    for (int j = 0; j < 4; j++) bias[j] = b2[(size_t)e * OUTD + n0 + nw + j * 16 + cc];

    f32x4 zero4 = {0.f, 0.f, 0.f, 0.f};
    f32x4 acc[4][4];
#pragma unroll
    for (int i = 0; i < 4; i++)
#pragma unroll
        for (int j = 0; j < 4; j++) acc[i][j] = zero4;

    // prefetch registers: A frags (bf16, no cvt needed) + raw f32 B rows
    bf16x8 ga[4];
    float4 braw[8];
#pragma unroll
    for (int p = 0; p < 4; p++) ga[p] = *(const bf16x8*)(Ag + (size_t)p * 32 * HID);
#pragma unroll
    for (int i = 0; i < 8; i++) braw[i] = *(const float4*)(Bgf + (size_t)i * OUTD);

    const int NIT = HID / BKG;   // 16
    for (int it = 0; it < NIT; ++it) {
        __hip_bfloat16* Ac = As[it & 1];
        __hip_bfloat16* Bc = Bs[it & 1];
        // convert (data arrived during previous MFMA phase) and write buf[cur]
        union { bf16x8 v8; __hip_bfloat16 h[8]; } gb[4];
#pragma unroll
        for (int i = 0; i < 8; i++) {
            gb[0].h[i] = __float2bfloat16(braw[i].x);
            gb[1].h[i] = __float2bfloat16(braw[i].y);
            gb[2].h[i] = __float2bfloat16(braw[i].z);
            gb[3].h[i] = __float2bfloat16(braw[i].w);
        }
#pragma unroll
        for (int p = 0; p < 4; p++) *(bf16x8*)(Ac + awbase + p * 2048) = ga[p];
#pragma unroll
        for (int j = 0; j < 4; j++) *(bf16x8*)(Bc + bwb[j]) = gb[j].v8;
        // issue next iter's loads; results not consumed until next write phase
        if (it + 1 < NIT) {
            int k1 = (it + 1) * BKG;
#pragma unroll
            for (int p = 0; p < 4; p++)
                ga[p] = *(const bf16x8*)(Ag + (size_t)p * 32 * HID + k1);
#pragma unroll
            for (int i = 0; i < 8; i++)
                braw[i] = *(const float4*)(Bgf + (size_t)(k1 + i) * OUTD);
        }
        __syncthreads();
#pragma unroll
        for (int kh = 0; kh < 2; ++kh) {
            int X = kh ? X1 : X0;
            bf16x8 af[4], bfr[4];
#pragma unroll
            for (int i = 0; i < 4; i++) af[i] = *(const bf16x8*)(Ac + A0 + i * 1024 + X);
#pragma unroll
            for (int j = 0; j < 4; j++) bfr[j] = *(const bf16x8*)(Bc + B0 + j * 1024 + X);
#pragma unroll
            for (int i = 0; i < 4; i++)
#pragma unroll
                for (int j = 0; j < 4; j++)
                    acc[i][j] = __builtin_amdgcn_mfma_f32_16x16x32_bf16(af[i], bfr[j],
                                                                        acc[i][j], 0, 0, 0);
        }
    }
#pragma unroll
    for (int i = 0; i < 4; i++)
#pragma unroll
        for (int r = 0; r < 4; r++) {
            int m = mw + i * 16 + q * 4 + r;
            int orow = rows_s[m];
            if (orow >= 0) {
                float* op = out + (size_t)orow * OUTD + n0 + nw + cc;
#pragma unroll
                for (int j = 0; j < 4; j++) op[j * 16] = acc[i][j][r] + bias[j];
            }
        }
}

extern "C" void kernel_launch(void* const* d_in, const int* in_sizes, int n_in,
                              void* d_out, int out_size, void* d_ws, size_t ws_size,
                              hipStream_t stream) {
    const float* z  = (const float*)d_in[0];
    const float* W1 = (const float*)d_in[1];
    const float* b1 = (const float*)d_in[2];
    const float* W2 = (const float*)d_in[3];
    const float* b2 = (const float*)d_in[4];
    float* out = (float*)d_out;

    char* ws = (char*)d_ws;
    int* counts = (int*)ws;
    int* ntl    = (int*)(ws + 64);
    int* texp   = (int*)(ws + 128);
    int* perm   = (int*)(ws + 256);
    int* bucket = (int*)(ws + 12544);
    __hip_bfloat16* zb  = (__hip_bfloat16*)(ws + 78080);
    __hip_bfloat16* Hb  = (__hip_bfloat16*)(ws + 602368);

    hipMemsetAsync(counts, 0, 64, stream);
    hipLaunchKernelGGL(route_kernel, dim3(BATCH / 32), dim3(256), 0, stream,
                       z, zb, counts, bucket);
    hipLaunchKernelGGL(scan_kernel, dim3(1), dim3(256), 0, stream,
                       counts, ntl, texp, perm, bucket);
    hipLaunchKernelGGL(gemm1_fast, dim3(HID / TNG, MAXTF), dim3(256), 0, stream,
                       zb, W1, b1, ntl, texp, perm, Hb);
    hipLaunchKernelGGL(gemm2_fast, dim3(OUTD / TNG, MAXTF), dim3(256), 0, stream,
                       Hb, W2, b2, ntl, texp, perm, out);
}